// Round 9
// baseline (325.884 us; speedup 1.0000x reference)
//
#include <hip/hip_runtime.h>

#define NB 256
#define CLIP_LIM 1024              // max(int(4.0*65536/256),1)
#define HSTRIDE 264                // 256+8: adjacent sub-hists shift bank pattern by 8
#define PSTRIDE 9                  // packed u16-pair entries per bin (s=0..8), gcd(9,32)=1

typedef float f32x4 __attribute__((ext_vector_type(4)));

// ---------------- Kernel 1: LINEAR histogram pass + in-kernel LUT build ----------------
// 512 blocks x 1024 thr; 8 blocks per (b,ty) band (2MB contiguous span each -> 256KB/block).
// NT img loads (don't pollute L3; bins stays resident for K2). Wave w serves tile column
// tx = w&7 -> wave-private sub-hists (parity split -> 32 tables). Blocks write per-block
// partials; the LAST block to arrive (device-scope acq_rel counter) reduces the band's
// 8 partials and builds the band's 8 LUTs (segmented scan, 4 tiles at a time).
__global__ __launch_bounds__(1024) void clahe_hist(const float* __restrict__ img,
                                                   unsigned int* __restrict__ bins,
                                                   unsigned int* __restrict__ part,
                                                   unsigned int* __restrict__ cnt,
                                                   float* __restrict__ lut) {
    const int blk  = blockIdx.x;         // 0..511
    const int band = blk >> 3;           // 0..63  (b*8 + ty)
    const int tid  = threadIdx.x;
    const int sub  = ((tid >> 6) << 1) | (tid & 1);   // 0..31: wave*2 + lane parity

    __shared__ int h[32 * HSTRIDE];      // 33,792 B (reused as hh[2048]+c[1024] in LUT phase)
    __shared__ int s_exc[4];
    __shared__ int s_last;

    #pragma unroll
    for (int k = 0; k < 9; ++k) {
        const int idx = tid + k * 1024;
        if (idx < 32 * HSTRIDE) h[idx] = 0;
    }
    __syncthreads();

    const size_t B0 = (size_t)blk * 16384;    // base quad index (band*131072 + j*16384)
    int* hw = &h[sub * HSTRIDE];

    #pragma unroll
    for (int k = 0; k < 16; ++k) {
        const size_t g = B0 + k * 1024 + tid;           // image-linear quad index
        const f32x4 v = __builtin_nontemporal_load(
            reinterpret_cast<const f32x4*>(img + g * 4));    // linear, read-once
        const int b0 = (int)fminf(fmaxf(v.x, 0.f), 255.f);
        const int b1 = (int)fminf(fmaxf(v.y, 0.f), 255.f);
        const int b2 = (int)fminf(fmaxf(v.z, 0.f), 255.f);
        const int b3 = (int)fminf(fmaxf(v.w, 0.f), 255.f);
        atomicAdd(&hw[b0], 1);
        atomicAdd(&hw[b1], 1);
        atomicAdd(&hw[b2], 1);
        atomicAdd(&hw[b3], 1);
        bins[g] = (unsigned)b0 | ((unsigned)b1 << 8) |
                  ((unsigned)b2 << 16) | ((unsigned)b3 << 24);   // linear, coalesced
    }
    __syncthreads();

    // write partials: 8 tile-columns x 256 bins; tables for tx: {2tx,2tx+1,2tx+16,2tx+17}
    #pragma unroll
    for (int e = tid; e < 2048; e += 1024) {
        const int tx = e >> 8;
        const int bn = e & 255;
        const int s = h[(2 * tx) * HSTRIDE + bn] + h[(2 * tx + 1) * HSTRIDE + bn] +
                      h[(2 * tx + 16) * HSTRIDE + bn] + h[(2 * tx + 17) * HSTRIDE + bn];
        part[(size_t)blk * 2048 + e] = (unsigned int)s;          // coalesced
    }

    // ---- last-arrival detection (threadfence reduction pattern)
    __threadfence();             // release: partials visible device-wide before counter bump
    __syncthreads();
    if (tid == 0) {
        const unsigned int old = __hip_atomic_fetch_add(&cnt[band], 1u,
                                     __ATOMIC_ACQ_REL, __HIP_MEMORY_SCOPE_AGENT);
        s_last = (old == 7u);
    }
    __syncthreads();
    if (!s_last) return;

    // ---- last block of the band: reduce 8 partials -> 8 tile LUTs
    __threadfence();             // acquire: other blocks' partials
    int* hh = h;                 // [2048] band hist sums (tx*256 + bin)
    int* c  = h + 2048;          // [1024] scan workspace
    for (int e = tid; e < 2048; e += 1024) {
        int s = 0;
        #pragma unroll
        for (int j = 0; j < 8; ++j)
            s += (int)part[(size_t)(band * 8 + j) * 2048 + e];
        hh[e] = s;
    }
    __syncthreads();

    #pragma unroll
    for (int g = 0; g < 2; ++g) {        // tiles g*4 .. g*4+3 in parallel
        const int t4  = tid >> 8;        // 0..3
        const int bin = tid & 255;
        const int tileIdx = g * 4 + t4;
        if (tid < 4) s_exc[tid] = 0;
        __syncthreads();
        const int sum = hh[tileIdx * 256 + bin];
        const int cl0 = min(sum, CLIP_LIM);
        atomicAdd(&s_exc[t4], sum - cl0);
        __syncthreads();
        const int excess   = s_exc[t4];
        const int add      = excess >> 8;
        const int residual = excess & 255;
        int step = 256 / (residual > 0 ? residual : 1);
        if (step < 1) step = 1;
        c[tid] = cl0 + add + ((residual > 0 && (bin % step) == 0) ? 1 : 0);
        __syncthreads();
        // segmented inclusive Hillis-Steele scan (256-wide segments)
        #pragma unroll
        for (int off = 1; off < NB; off <<= 1) {
            const int v = (bin >= off) ? c[tid - off] : 0;
            __syncthreads();
            c[tid] += v;
            __syncthreads();
        }
        float lv = rintf((float)c[tid] * (255.0f / 65536.0f));   // exact; RTE == jnp.round
        lut[(size_t)(band * 8 + tileIdx) * NB + bin] = fminf(fmaxf(lv, 0.f), 255.f);
        __syncthreads();
    }
}

// ---------------- Kernel 2: bilinear LUT apply (byte-identical to R7) ----------------
// Block = (image, even row pair); packed fixed-point 8.8 tables; ONE ds_read_b32 per pixel.
// All f32 arithmetic exact (integers x k/256 weights, numerators < 2^24) -> bit-exact vs ref.
__global__ __launch_bounds__(256, 8) void clahe_apply(const unsigned int* __restrict__ bins,
                                                      const float* __restrict__ lut,
                                                      float* __restrict__ out) {
    const int bi  = blockIdx.x;
    const int b   = bi >> 10;
    const int y0  = (bi & 1023) * 2;     // even row pair; never straddles a y-segment boundary
    const int tid = threadIdx.x;

    __shared__ unsigned int T[2 * NB * PSTRIDE];   // 18,432 B

    {   // ---- build packed y-blended tables for both rows (tid == bin)
        const float yf  = (float)y0 * (1.0f / 256.0f) - 0.5f;
        const float y1f = floorf(yf);
        const int y1 = min(max((int)y1f, 0), 7);
        const int y2 = min(max((int)y1f + 1, 0), 7);
        const float* lb = lut + ((size_t)b << 14);
        float la[8], lc[8];
        #pragma unroll
        for (int xc = 0; xc < 8; ++xc) {
            la[xc] = lb[(y1 * 8 + xc) * NB + tid];
            lc[xc] = lb[(y2 * 8 + xc) * NB + tid];
        }
        #pragma unroll
        for (int r = 0; r < 2; ++r) {
            const float q = (float)((y0 + r + 128) & 255);   // ya*256, integer
            float tv[10];
            #pragma unroll
            for (int k = 0; k < 10; ++k) {
                const int kc = (k == 0) ? 0 : ((k - 1 > 7) ? 7 : k - 1);
                tv[k] = la[kc] * (256.0f - q) + lc[kc] * q;  // exact integer <= 65280
            }
            unsigned int* Tr = &T[r * NB * PSTRIDE + tid * PSTRIDE];
            #pragma unroll
            for (int s = 0; s < 9; ++s)
                Tr[s] = (unsigned int)tv[s] | ((unsigned int)tv[s + 1] << 16);
        }
    }
    __syncthreads();

    const size_t imgbase = ((size_t)b << 22) + (size_t)y0 * 2048;
    #pragma unroll
    for (int it = 0; it < 4; ++it) {
        const int r = it >> 1;
        const int i = (it & 1) * 256 + tid;          // float4-word index in row, 0..511
        const size_t prow = imgbase + (size_t)r * 2048;
        const unsigned int w = bins[(prow >> 2) + i];
        const unsigned int* Tr = &T[r * NB * PSTRIDE];
        const int x   = i * 4;
        const int s   = (x + 128) >> 8;              // 0..8, constant within quad
        const float xa0 = (float)((x + 128) & 255);  // numerator; no wrap within j=0..3
        float res[4];
        #pragma unroll
        for (int j = 0; j < 4; ++j) {
            const int bn = (w >> (8 * j)) & 255;
            const unsigned int u = Tr[bn * PSTRIDE + s];      // one ds_read_b32
            const float a  = (float)(u & 0xFFFFu);            // left*256 (exact int)
            const float bb = (float)(u >> 16);                // right*256 (exact int)
            const float xa = (xa0 + (float)j) * (1.0f / 256.0f);
            const float v  = a + (bb - a) * xa;               // exact, = result*256
            res[j] = fminf(fmaxf(rintf(v * (1.0f / 256.0f)), 0.f), 255.f);
        }
        const f32x4 o = { res[0], res[1], res[2], res[3] };
        __builtin_nontemporal_store(o, reinterpret_cast<f32x4*>(out + prow + i * 4));
    }
}

extern "C" void kernel_launch(void* const* d_in, const int* in_sizes, int n_in,
                              void* d_out, int out_size, void* d_ws, size_t ws_size,
                              hipStream_t stream) {
    const float* img = (const float*)d_in[0];
    float* out = (float*)d_out;
    char* ws = (char*)d_ws;
    float*        lut  = (float*)ws;                              // 512 KiB
    unsigned int* part = (unsigned int*)(ws + 524288);            // 4 MiB
    unsigned int* bins = (unsigned int*)(ws + 524288 + 4194304);  // 33.5 MB
    unsigned int* cnt  = (unsigned int*)(ws + 524288 + 4194304 + 33554432);  // 64 u32

    hipMemsetAsync(cnt, 0, 64 * sizeof(unsigned int), stream);    // capture-legal memset node
    clahe_hist<<<512, 1024, 0, stream>>>(img, bins, part, cnt, lut);
    clahe_apply<<<8 * 1024, 256, 0, stream>>>(bins, lut, out);
}

// Round 10
// 68.437 us; speedup vs baseline: 4.7618x; 4.7618x over previous
//
#include <hip/hip_runtime.h>

#define NB 256
#define CLIP_LIM 1024              // max(int(4.0*65536/256),1)
#define HSTRIDE 264                // 256+8: adjacent sub-hists shift bank pattern by 8
#define PSTRIDE 9                  // packed u16-pair entries per bin (s=0..8), gcd(9,32)=1

typedef float f32x4 __attribute__((ext_vector_type(4)));

// ---------------- Kernel 1: LINEAR histogram pass ----------------
// 512 blocks x 1024 thr; 8 blocks per (b,ty) band (2MB contiguous). Each block reads a
// contiguous 256KB span with NT loads. Aligned 64-quad wave reads (256px) lie in ONE tile
// column, and wave w always serves tx = w&7 -> wave-private sub-hists (parity split -> 32
// tables). Outputs: packed u8 bins (image-linear, coalesced; L3-resident for K2) +
// per-block partial hists (no atomics). NO device-scope fences (R9 lesson: per-block
// agent-scope fencing costs L2 writebacks on non-coherent XCD L2s).
__global__ __launch_bounds__(1024) void clahe_hist(const float* __restrict__ img,
                                                   unsigned int* __restrict__ bins,
                                                   unsigned int* __restrict__ part) {
    const int blk  = blockIdx.x;         // 0..511
    const int tid  = threadIdx.x;
    const int sub  = ((tid >> 6) << 1) | (tid & 1);   // 0..31: wave*2 + lane parity

    __shared__ int h[32 * HSTRIDE];      // 33,792 B

    #pragma unroll
    for (int k = 0; k < 9; ++k) {
        const int idx = tid + k * 1024;
        if (idx < 32 * HSTRIDE) h[idx] = 0;
    }
    __syncthreads();

    const size_t B0 = (size_t)blk * 16384;    // base quad index (band*131072 + j*16384)
    int* hw = &h[sub * HSTRIDE];

    #pragma unroll
    for (int k = 0; k < 16; ++k) {
        const size_t g = B0 + k * 1024 + tid;           // image-linear quad index
        const f32x4 v = __builtin_nontemporal_load(
            reinterpret_cast<const f32x4*>(img + g * 4));    // linear, read-once
        const int b0 = (int)fminf(fmaxf(v.x, 0.f), 255.f);
        const int b1 = (int)fminf(fmaxf(v.y, 0.f), 255.f);
        const int b2 = (int)fminf(fmaxf(v.z, 0.f), 255.f);
        const int b3 = (int)fminf(fmaxf(v.w, 0.f), 255.f);
        atomicAdd(&hw[b0], 1);
        atomicAdd(&hw[b1], 1);
        atomicAdd(&hw[b2], 1);
        atomicAdd(&hw[b3], 1);
        bins[g] = (unsigned)b0 | ((unsigned)b1 << 8) |
                  ((unsigned)b2 << 16) | ((unsigned)b3 << 24);   // linear, coalesced
    }
    __syncthreads();

    // write partials: 8 tile-columns x 256 bins; tables for tx: {2tx,2tx+1,2tx+16,2tx+17}
    #pragma unroll
    for (int e = tid; e < 2048; e += 1024) {
        const int tx = e >> 8;
        const int bn = e & 255;
        const int s = h[(2 * tx) * HSTRIDE + bn] + h[(2 * tx + 1) * HSTRIDE + bn] +
                      h[(2 * tx + 16) * HSTRIDE + bn] + h[(2 * tx + 17) * HSTRIDE + bn];
        part[(size_t)blk * 2048 + e] = (unsigned int)s;          // coalesced
    }
}

// ---------------- Kernel 1b: reduce partials -> clip/redistribute -> scan -> LUT ----------------
__global__ __launch_bounds__(256) void clahe_lut(const unsigned int* __restrict__ part,
                                                 float* __restrict__ lut) {
    const int t    = blockIdx.x;         // tile = band*8 + tx = b*64 + ty*8 + tx
    const int band = t >> 3;
    const int tx   = t & 7;
    const int tid  = threadIdx.x;        // bin

    __shared__ int c[NB];
    __shared__ int s_excess;
    if (tid == 0) s_excess = 0;
    __syncthreads();

    int sum = 0;
    #pragma unroll
    for (int j = 0; j < 8; ++j)
        sum += (int)part[(size_t)(band * 8 + j) * 2048 + tx * 256 + tid];

    const int clipped0 = min(sum, CLIP_LIM);
    atomicAdd(&s_excess, sum - clipped0);
    __syncthreads();

    const int excess   = s_excess;
    const int add      = excess >> 8;
    const int residual = excess & 255;
    int step = 256 / (residual > 0 ? residual : 1);
    if (step < 1) step = 1;
    c[tid] = clipped0 + add + ((residual > 0 && (tid % step) == 0) ? 1 : 0);
    __syncthreads();

    // inclusive Hillis-Steele scan over 256 bins
    #pragma unroll
    for (int off = 1; off < NB; off <<= 1) {
        const int v = (tid >= off) ? c[tid - off] : 0;
        __syncthreads();
        c[tid] += v;
        __syncthreads();
    }

    float lv = rintf((float)c[tid] * (255.0f / 65536.0f));   // exact; RTE == jnp.round
    lut[t * NB + tid] = fminf(fmaxf(lv, 0.f), 255.f);
}

// ---------------- Kernel 2: bilinear LUT apply ----------------
// Block = (image, even row pair); packed fixed-point 8.8 tables; ONE ds_read_b32 per pixel.
// All f32 arithmetic exact (integers x k/256 weights, numerators < 2^24) -> bit-exact vs ref.
__global__ __launch_bounds__(256, 8) void clahe_apply(const unsigned int* __restrict__ bins,
                                                      const float* __restrict__ lut,
                                                      float* __restrict__ out) {
    const int bi  = blockIdx.x;
    const int b   = bi >> 10;
    const int y0  = (bi & 1023) * 2;     // even row pair; never straddles a y-segment boundary
    const int tid = threadIdx.x;

    __shared__ unsigned int T[2 * NB * PSTRIDE];   // 18,432 B

    {   // ---- build packed y-blended tables for both rows (tid == bin)
        const float yf  = (float)y0 * (1.0f / 256.0f) - 0.5f;
        const float y1f = floorf(yf);
        const int y1 = min(max((int)y1f, 0), 7);
        const int y2 = min(max((int)y1f + 1, 0), 7);
        const float* lb = lut + ((size_t)b << 14);
        float la[8], lc[8];
        #pragma unroll
        for (int xc = 0; xc < 8; ++xc) {
            la[xc] = lb[(y1 * 8 + xc) * NB + tid];
            lc[xc] = lb[(y2 * 8 + xc) * NB + tid];
        }
        #pragma unroll
        for (int r = 0; r < 2; ++r) {
            const float q = (float)((y0 + r + 128) & 255);   // ya*256, integer
            float tv[10];
            #pragma unroll
            for (int k = 0; k < 10; ++k) {
                const int kc = (k == 0) ? 0 : ((k - 1 > 7) ? 7 : k - 1);
                tv[k] = la[kc] * (256.0f - q) + lc[kc] * q;  // exact integer <= 65280
            }
            unsigned int* Tr = &T[r * NB * PSTRIDE + tid * PSTRIDE];
            #pragma unroll
            for (int s = 0; s < 9; ++s)
                Tr[s] = (unsigned int)tv[s] | ((unsigned int)tv[s + 1] << 16);
        }
    }
    __syncthreads();

    const size_t imgbase = ((size_t)b << 22) + (size_t)y0 * 2048;
    #pragma unroll
    for (int it = 0; it < 4; ++it) {
        const int r = it >> 1;
        const int i = (it & 1) * 256 + tid;          // float4-word index in row, 0..511
        const size_t prow = imgbase + (size_t)r * 2048;
        const unsigned int w = bins[(prow >> 2) + i];
        const unsigned int* Tr = &T[r * NB * PSTRIDE];
        const int x   = i * 4;
        const int s   = (x + 128) >> 8;              // 0..8, constant within quad
        const float xa0 = (float)((x + 128) & 255);  // numerator; no wrap within j=0..3
        float res[4];
        #pragma unroll
        for (int j = 0; j < 4; ++j) {
            const int bn = (w >> (8 * j)) & 255;
            const unsigned int u = Tr[bn * PSTRIDE + s];      // one ds_read_b32
            const float a  = (float)(u & 0xFFFFu);            // left*256 (exact int)
            const float bb = (float)(u >> 16);                // right*256 (exact int)
            const float xa = (xa0 + (float)j) * (1.0f / 256.0f);
            const float v  = a + (bb - a) * xa;               // exact, = result*256
            res[j] = fminf(fmaxf(rintf(v * (1.0f / 256.0f)), 0.f), 255.f);
        }
        const f32x4 o = { res[0], res[1], res[2], res[3] };
        __builtin_nontemporal_store(o, reinterpret_cast<f32x4*>(out + prow + i * 4));
    }
}

extern "C" void kernel_launch(void* const* d_in, const int* in_sizes, int n_in,
                              void* d_out, int out_size, void* d_ws, size_t ws_size,
                              hipStream_t stream) {
    const float* img = (const float*)d_in[0];
    float* out = (float*)d_out;
    char* ws = (char*)d_ws;
    float*        lut  = (float*)ws;                         // 512 KiB
    unsigned int* bins = (unsigned int*)(ws + 524288);       // 33.5 MB
    unsigned int* part = (unsigned int*)(ws + 524288 + 33554432);  // 4 MiB

    clahe_hist<<<512, 1024, 0, stream>>>(img, bins, part);
    clahe_lut<<<512, 256, 0, stream>>>(part, lut);
    clahe_apply<<<8 * 1024, 256, 0, stream>>>(bins, lut, out);
}